// Round 3
// baseline (514.546 us; speedup 1.0000x reference)
//
#include <hip/hip_runtime.h>

// Dynamic filter layer, 'valid', stride 1:
// out[b,i,j,c] = sum_{di,dj} x[b,i+di,j+dj,c] * flow[b,i,j,di*K+dj]
// B=8, H=W=256, C=64, K=5, Ho=Wo=252. All fp32.
//
// R5: reg-staged LDS for x (plain global->VGPR->ds_write, NOT global_load_lds:
// R3 showed the LDS-DMA path explodes HBM traffic 7-11x on this stencil).
//  - Each block loads its unique x tile (10 rows x 20 px x 64 ch = 51 KB)
//    exactly once, coalesced: 13 float4 loads/thread (was 50 with 5x dj
//    redundancy). The dj-reuse is served from LDS (~120 cyc fixed latency).
//  - 2-row groups, double-buffered: iter g does {ds_write g+1 (drained),
//    issue loads g+2, compute g from LDS}. __syncthreads' vmcnt(0) drain
//    lands after a full compute phase -> load latency hidden (T14, 2-ahead).
//  - flow weights LDS layout unchanged from R4 (FROW=8 pad, b128+b32 reads,
//    jj lanes on banks {0,8,16,24}).
//  - x LDS patterns: writes linear (2-way, free), reads q*4-word stride
//    (2-way, free per m136).
// LDS 20.0 + 15.0 = 35.8 KB -> 4 blocks/CU cap.

constexpr int B  = 8;
constexpr int H  = 256;
constexpr int W  = 256;
constexpr int C  = 64;
constexpr int K  = 5;
constexpr int Ho = H - K + 1;            // 252
constexpr int Wo = W - K + 1;            // 252
constexpr int CQ = C / 4;                // 16 float4 quads per pixel
constexpr int R  = 6;                    // output rows per block (Ho % R == 0)
constexpr int SEG = Ho / R;              // 42 row segments
constexpr int JT  = 16;                  // j-pixels per block (16 j x 16 q)
constexpr int JB  = (Wo + JT - 1) / JT;  // 16 j blocks (last partial)
constexpr int NR  = R + K - 1;           // 10 x rows touched per block
constexpr int PX  = JT + K - 1;          // 20 x-pixels staged per row
constexpr int FROW = 8;                  // filter row padded 5 -> 8 floats
constexpr int GRP = 2;                   // x rows per stage group
constexpr int NG  = NR / GRP;            // 5 groups
constexpr int QPG = GRP * PX * CQ;       // 640 float4 chunks per group
constexpr int STEPS = (QPG + 255) / 256; // 3 cooperative copy steps

typedef float vf4 __attribute__((ext_vector_type(4)));

__global__ __launch_bounds__(256) void dfl_kernel(
    const float* __restrict__ x,
    const float* __restrict__ flow,
    float* __restrict__ out)
{
    __shared__ float4 sx[2 * QPG];              // 20 KiB, double-buffered x
    __shared__ float  sf[R * JT * K * FROW];    // 15 KiB, padded flow

    const int t  = threadIdx.x;
    const int q  = t & (CQ - 1);          // channel quad 0..15
    const int jj = t >> 4;                // j within block 0..15

    int bid = blockIdx.x;
    const int jb  = bid % JB;  bid /= JB;
    const int seg = bid % SEG; bid /= SEG;
    const int b   = bid;

    const int j0 = jb * JT;
    const int j  = j0 + jj;
    const int i0 = seg * R;

    // ---- Stage flow tile: [ii][jj][di][FROW], coalesced reads ----
    {
        const float* fsrc = flow + ((size_t)(b * Ho + i0) * Wo + j0) * (K * K);
        #pragma unroll
        for (int step = 0; step < (R * JT * K * K + 255) / 256; ++step) {
            const int e = step * 256 + t;
            if (e < R * JT * K * K) {
                const int ii  = e / (JT * K * K);
                const int rem = e - ii * (JT * K * K);
                const int pj  = rem / (K * K);
                const int tap = rem - pj * (K * K);
                const int di  = tap / K;
                const int dj  = tap - di * K;
                float v = 0.f;
                if (j0 + pj < Wo)                 // guard: last j-block OOB
                    v = fsrc[(size_t)ii * (Wo * K * K) + pj * (K * K) + tap];
                sf[((ii * JT + pj) * K + di) * FROW + dj] = v;
            }
        }
    }

    // ---- x staging helpers (all g compile-time after unroll) ----
    // chunk c (< QPG): rr = row in group, px = pixel 0..19, qd = channel quad
    auto issue = [&](int g, float4* dst) {      // global -> regs, no wait
        #pragma unroll
        for (int s = 0; s < STEPS; ++s) {
            const int c = s * 256 + t;
            if (c < QPG) {
                const int rr = c / (PX * CQ);
                const int cw = c - rr * (PX * CQ);
                const int px = cw >> 4;
                const int qd = cw & 15;
                const int row = i0 + g * GRP + rr;        // <= 255 always
                int gpx = j0 + px; if (gpx > W - 1) gpx = W - 1; // edge clamp
                dst[s] = *((const float4*)x +
                           ((size_t)(b * H + row) * W + gpx) * CQ + qd);
            }
        }
    };
    auto commit = [&](int buf, const float4* src) {  // regs -> LDS
        #pragma unroll
        for (int s = 0; s < STEPS; ++s) {
            const int c = s * 256 + t;
            if (c < QPG) sx[buf * QPG + c] = src[s];
        }
    };

    float4 acc[R];
    #pragma unroll
    for (int ii = 0; ii < R; ++ii) acc[ii] = make_float4(0.f, 0.f, 0.f, 0.f);

    float4 stgA[STEPS], stgB[STEPS];      // group h lives in (h&1)?B:A
    issue(0, stgA);
    issue(1, stgB);
    commit(0, stgA);                      // waits only stgA's loads (vmcnt)
    __syncthreads();                      // buf0 visible; stgB drained

    #pragma unroll
    for (int g = 0; g < NG; ++g) {
        if (g + 2 < NG) issue(g + 2, (g & 1) ? stgB : stgA);  // in flight
        if (g + 1 < NG) commit((g + 1) & 1, ((g + 1) & 1) ? stgB : stgA);

        // ---- compute group g from sx[g&1] ----
        #pragma unroll
        for (int rr = 0; rr < GRP; ++rr) {
            const int r = g * GRP + rr;               // static after unroll
            const float4* xr = &sx[(g & 1) * QPG + rr * (PX * CQ)];
            float4 xv[K];
            #pragma unroll
            for (int dj = 0; dj < K; ++dj)
                xv[dj] = xr[(jj + dj) * CQ + q];
            #pragma unroll
            for (int ii = 0; ii < R; ++ii) {
                const int di = r - ii;                // tap row for output ii
                if (di < 0 || di >= K) continue;      // compile-time resolved
                const float* fp = &sf[((ii * JT + jj) * K + di) * FROW];
                const vf4   w4 = *(const vf4*)fp;     // ds_read_b128
                const float w5 = fp[4];               // ds_read_b32
                const float wt[K] = {w4.x, w4.y, w4.z, w4.w, w5};
                #pragma unroll
                for (int dj = 0; dj < K; ++dj) {
                    acc[ii].x += xv[dj].x * wt[dj];
                    acc[ii].y += xv[dj].y * wt[dj];
                    acc[ii].z += xv[dj].z * wt[dj];
                    acc[ii].w += xv[dj].w * wt[dj];
                }
            }
        }
        if (g + 1 < NG) __syncthreads();  // drains g+2 loads; buf g+1 visible
    }

    if (j < Wo) {
        float* ob = out + (((size_t)(b * Ho + i0) * Wo + j) * CQ + q) * 4;
        #pragma unroll
        for (int ii = 0; ii < R; ++ii) {
            vf4 v = {acc[ii].x, acc[ii].y, acc[ii].z, acc[ii].w};
            __builtin_nontemporal_store(v, (vf4*)(ob + (size_t)ii * (Wo * CQ) * 4));
        }
    }
}

extern "C" void kernel_launch(void* const* d_in, const int* in_sizes, int n_in,
                              void* d_out, int out_size, void* d_ws, size_t ws_size,
                              hipStream_t stream) {
    const float* x    = (const float*)d_in[0];
    const float* flow = (const float*)d_in[1];
    // d_in[2] is ksize (scalar), fixed at 5 — baked in as constexpr.
    float* out = (float*)d_out;

    const int grid = B * SEG * JB;        // 8 * 42 * 16 = 5376 blocks
    dfl_kernel<<<grid, 256, 0, stream>>>(x, flow, out);
}

// Round 6
// 392.512 us; speedup vs baseline: 1.3109x; 1.3109x over previous
//
#include <hip/hip_runtime.h>

// Dynamic filter layer, 'valid', stride 1:
// out[b,i,j,c] = sum_{di,dj} x[b,i+di,j+dj,c] * flow[b,i,j,di*K+dj]
// B=8, H=W=256, C=64, K=5, Ho=Wo=252. All fp32.
//
// R7 = R4 + __launch_bounds__(256,4) ONLY (no sched_barrier pins).
// R4 post-mortem: VGPR=80 (compiler occupancy heuristic) couldn't hold the
// 3-row prefetch ring, so the scheduler sank every x-load to just before its
// use -> 50 serialized ~500cy L2/L3 exposures/wave ~= the whole 34.5K-cycle
// wave lifetime. (x row stride is exactly 64KB -> L1 set-aliasing, so loads
// hit L2/L3 latency, not L1.) With a 128-VGPR budget the machine scheduler's
// latency-driven hoisting should keep the ring alive; VGPR_Count is the probe.
// (R6's sched_barrier variant died twice on container acquire; dropping the
// intrinsic both hedges a toolchain hang and tests the budget-only theory.)
// Kept from R4: direct per-thread x loads (R3/R5 proved LDS staging of x
// regresses 3-5x), padded-flow LDS (b128+b32, bank-clean), NT output stores.

constexpr int B  = 8;
constexpr int H  = 256;
constexpr int W  = 256;
constexpr int C  = 64;
constexpr int K  = 5;
constexpr int Ho = H - K + 1;            // 252
constexpr int Wo = W - K + 1;            // 252
constexpr int CQ = C / 4;                // 16 float4 quads per pixel
constexpr int R  = 6;                    // outputs per thread along i (Ho % R == 0)
constexpr int SEG = Ho / R;              // 42 row segments
constexpr int JT  = 16;                  // j-pixels per block (16 j x 16 q = 256 thr)
constexpr int JB  = (Wo + JT - 1) / JT;  // 16 j blocks (last partial)
constexpr int NR  = R + K - 1;           // 10 x rows touched per block
constexpr int FROW = 8;                  // filter row padded 5 -> 8 floats

typedef float vf4 __attribute__((ext_vector_type(4)));

__global__ __launch_bounds__(256, 4) void dfl_kernel(
    const float* __restrict__ x,
    const float* __restrict__ flow,
    float* __restrict__ out)
{
    __shared__ float sf[R * JT * K * FROW];   // 15 KiB, padded flow

    const int t  = threadIdx.x;
    const int q  = t & (CQ - 1);          // channel quad 0..15
    const int jj = t >> 4;                // j within block 0..15

    int bid = blockIdx.x;
    const int jb  = bid % JB;  bid /= JB;
    const int seg = bid % SEG; bid /= SEG;
    const int b   = bid;

    const int j0 = jb * JT;
    const int j  = j0 + jj;
    const int i0 = seg * R;

    // ---- x window base (clamped for edge block; store is guarded) ----
    const int jx = j < Wo ? j : Wo - 1;
    const float4* xq = (const float4*)x + ((size_t)(b * H + i0) * W + jx) * CQ + q;

    // ---- issue x rows 0,1 BEFORE flow staging: latency hides under it ----
    float4 xb[3][K];                      // 3-row register ring (60 VGPRs)
    #pragma unroll
    for (int dj = 0; dj < K; ++dj) xb[0][dj] = xq[dj * CQ];
    #pragma unroll
    for (int dj = 0; dj < K; ++dj) xb[1][dj] = xq[(size_t)(W * CQ) + dj * CQ];

    // ---- Stage flow tile: [ii][jj][di][FROW], coalesced reads ----
    {
        const float* fsrc = flow + ((size_t)(b * Ho + i0) * Wo + j0) * (K * K);
        #pragma unroll
        for (int step = 0; step < (R * JT * K * K + 255) / 256; ++step) {
            const int e = step * 256 + t;
            if (e < R * JT * K * K) {
                const int ii  = e / (JT * K * K);
                const int rem = e - ii * (JT * K * K);
                const int pj  = rem / (K * K);
                const int tap = rem - pj * (K * K);
                const int di  = tap / K;
                const int dj  = tap - di * K;
                float v = 0.f;
                if (j0 + pj < Wo)                 // guard: last j-block OOB
                    v = fsrc[(size_t)ii * (Wo * K * K) + pj * (K * K) + tap];
                sf[((ii * JT + pj) * K + di) * FROW + dj] = v;
            }
        }
    }
    __syncthreads();

    float4 acc[R];
    #pragma unroll
    for (int ii = 0; ii < R; ++ii) acc[ii] = make_float4(0.f, 0.f, 0.f, 0.f);

    #pragma unroll
    for (int r = 0; r < NR; ++r) {        // fully unrolled: all indices static
        if (r + 2 < NR) {                 // issue row r+2 before computing row r
            #pragma unroll
            for (int dj = 0; dj < K; ++dj)
                xb[(r + 2) % 3][dj] = xq[(size_t)(r + 2) * (W * CQ) + dj * CQ];
        }
        const float4* xrow = xb[r % 3];
        #pragma unroll
        for (int ii = 0; ii < R; ++ii) {
            const int di = r - ii;             // tap row for output ii
            if (di < 0 || di >= K) continue;   // compile-time resolved
            const float* fp = &sf[((ii * JT + jj) * K + di) * FROW];
            const vf4   w4 = *(const vf4*)fp;  // ds_read_b128
            const float w5 = fp[4];            // ds_read_b32
            const float wt[K] = {w4.x, w4.y, w4.z, w4.w, w5};
            #pragma unroll
            for (int dj = 0; dj < K; ++dj) {
                acc[ii].x += xrow[dj].x * wt[dj];
                acc[ii].y += xrow[dj].y * wt[dj];
                acc[ii].z += xrow[dj].z * wt[dj];
                acc[ii].w += xrow[dj].w * wt[dj];
            }
        }
    }

    if (j < Wo) {
        float* ob = out + (((size_t)(b * Ho + i0) * Wo + j) * CQ + q) * 4;
        #pragma unroll
        for (int ii = 0; ii < R; ++ii) {
            vf4 v = {acc[ii].x, acc[ii].y, acc[ii].z, acc[ii].w};
            __builtin_nontemporal_store(v, (vf4*)(ob + (size_t)ii * (Wo * CQ) * 4));
        }
    }
}

extern "C" void kernel_launch(void* const* d_in, const int* in_sizes, int n_in,
                              void* d_out, int out_size, void* d_ws, size_t ws_size,
                              hipStream_t stream) {
    const float* x    = (const float*)d_in[0];
    const float* flow = (const float*)d_in[1];
    // d_in[2] is ksize (scalar), fixed at 5 — baked in as constexpr.
    float* out = (float*)d_out;

    const int grid = B * SEG * JB;        // 8 * 42 * 16 = 5376 blocks
    dfl_kernel<<<grid, 256, 0, stream>>>(x, flow, out);
}

// Round 7
// 311.264 us; speedup vs baseline: 1.6531x; 1.2610x over previous
//
#include <hip/hip_runtime.h>

// Dynamic filter layer, 'valid', stride 1:
// out[b,i,j,c] = sum_{di,dj} x[b,i+di,j+dj,c] * flow[b,i,j,di*K+dj]
// B=8, H=W=256, C=64, K=5, Ho=Wo=252. All fp32.
//
// R8 = R4 + __launch_bounds__(256,2).
// Session regalloc law (R3/R7 evidence): (256,4) -> 64-VGPR cap -> spills
// (WRITE_SIZE 127->360 MB, FETCH 107->261 MB, dur 224us). (no arg) -> 80,
// scheduler sinks the prefetch ring. Observed mapping cap ~= 256/arg2, so
// (256,2) -> 128-VGPR cap: enough for the 3-row ring (~110 live) without
// spilling, targeting 4 waves/SIMD.
// Probe: VGPR_Count must land 100-128 with FETCH/WRITE flat (no spills).
// Kept from R4: direct per-thread x loads (R3/R5: LDS-staging x regresses),
// padded-flow LDS (b128+b32 reads, jj lanes on banks {0,8,16,24}), 3-row
// register ring with 2-row-ahead issue, NT output stores.

constexpr int B  = 8;
constexpr int H  = 256;
constexpr int W  = 256;
constexpr int C  = 64;
constexpr int K  = 5;
constexpr int Ho = H - K + 1;            // 252
constexpr int Wo = W - K + 1;            // 252
constexpr int CQ = C / 4;                // 16 float4 quads per pixel
constexpr int R  = 6;                    // outputs per thread along i (Ho % R == 0)
constexpr int SEG = Ho / R;              // 42 row segments
constexpr int JT  = 16;                  // j-pixels per block (16 j x 16 q = 256 thr)
constexpr int JB  = (Wo + JT - 1) / JT;  // 16 j blocks (last partial)
constexpr int NR  = R + K - 1;           // 10 x rows touched per block
constexpr int FROW = 8;                  // filter row padded 5 -> 8 floats

typedef float vf4 __attribute__((ext_vector_type(4)));

__global__ __launch_bounds__(256, 2) void dfl_kernel(
    const float* __restrict__ x,
    const float* __restrict__ flow,
    float* __restrict__ out)
{
    __shared__ float sf[R * JT * K * FROW];   // 15 KiB, padded flow

    const int t  = threadIdx.x;
    const int q  = t & (CQ - 1);          // channel quad 0..15
    const int jj = t >> 4;                // j within block 0..15

    int bid = blockIdx.x;
    const int jb  = bid % JB;  bid /= JB;
    const int seg = bid % SEG; bid /= SEG;
    const int b   = bid;

    const int j0 = jb * JT;
    const int j  = j0 + jj;
    const int i0 = seg * R;

    // ---- x window base (clamped for edge block; store is guarded) ----
    const int jx = j < Wo ? j : Wo - 1;
    const float4* xq = (const float4*)x + ((size_t)(b * H + i0) * W + jx) * CQ + q;

    // ---- issue x rows 0,1 BEFORE flow staging: latency hides under it ----
    float4 xb[3][K];                      // 3-row register ring (60 VGPRs)
    #pragma unroll
    for (int dj = 0; dj < K; ++dj) xb[0][dj] = xq[dj * CQ];
    #pragma unroll
    for (int dj = 0; dj < K; ++dj) xb[1][dj] = xq[(size_t)(W * CQ) + dj * CQ];

    // ---- Stage flow tile: [ii][jj][di][FROW], coalesced reads ----
    {
        const float* fsrc = flow + ((size_t)(b * Ho + i0) * Wo + j0) * (K * K);
        #pragma unroll
        for (int step = 0; step < (R * JT * K * K + 255) / 256; ++step) {
            const int e = step * 256 + t;
            if (e < R * JT * K * K) {
                const int ii  = e / (JT * K * K);
                const int rem = e - ii * (JT * K * K);
                const int pj  = rem / (K * K);
                const int tap = rem - pj * (K * K);
                const int di  = tap / K;
                const int dj  = tap - di * K;
                float v = 0.f;
                if (j0 + pj < Wo)                 // guard: last j-block OOB
                    v = fsrc[(size_t)ii * (Wo * K * K) + pj * (K * K) + tap];
                sf[((ii * JT + pj) * K + di) * FROW + dj] = v;
            }
        }
    }
    __syncthreads();

    float4 acc[R];
    #pragma unroll
    for (int ii = 0; ii < R; ++ii) acc[ii] = make_float4(0.f, 0.f, 0.f, 0.f);

    #pragma unroll
    for (int r = 0; r < NR; ++r) {        // fully unrolled: all indices static
        if (r + 2 < NR) {                 // issue row r+2 before computing row r
            #pragma unroll
            for (int dj = 0; dj < K; ++dj)
                xb[(r + 2) % 3][dj] = xq[(size_t)(r + 2) * (W * CQ) + dj * CQ];
        }
        const float4* xrow = xb[r % 3];
        #pragma unroll
        for (int ii = 0; ii < R; ++ii) {
            const int di = r - ii;             // tap row for output ii
            if (di < 0 || di >= K) continue;   // compile-time resolved
            const float* fp = &sf[((ii * JT + jj) * K + di) * FROW];
            const vf4   w4 = *(const vf4*)fp;  // ds_read_b128
            const float w5 = fp[4];            // ds_read_b32
            const float wt[K] = {w4.x, w4.y, w4.z, w4.w, w5};
            #pragma unroll
            for (int dj = 0; dj < K; ++dj) {
                acc[ii].x += xrow[dj].x * wt[dj];
                acc[ii].y += xrow[dj].y * wt[dj];
                acc[ii].z += xrow[dj].z * wt[dj];
                acc[ii].w += xrow[dj].w * wt[dj];
            }
        }
    }

    if (j < Wo) {
        float* ob = out + (((size_t)(b * Ho + i0) * Wo + j) * CQ + q) * 4;
        #pragma unroll
        for (int ii = 0; ii < R; ++ii) {
            vf4 v = {acc[ii].x, acc[ii].y, acc[ii].z, acc[ii].w};
            __builtin_nontemporal_store(v, (vf4*)(ob + (size_t)ii * (Wo * CQ) * 4));
        }
    }
}

extern "C" void kernel_launch(void* const* d_in, const int* in_sizes, int n_in,
                              void* d_out, int out_size, void* d_ws, size_t ws_size,
                              hipStream_t stream) {
    const float* x    = (const float*)d_in[0];
    const float* flow = (const float*)d_in[1];
    // d_in[2] is ksize (scalar), fixed at 5 — baked in as constexpr.
    float* out = (float*)d_out;

    const int grid = B * SEG * JB;        // 8 * 42 * 16 = 5376 blocks
    dfl_kernel<<<grid, 256, 0, stream>>>(x, flow, out);
}

// Round 8
// 257.471 us; speedup vs baseline: 1.9985x; 1.2089x over previous
//
#include <hip/hip_runtime.h>

// Dynamic filter layer, 'valid', stride 1:
// out[b,i,j,c] = sum_{di,dj} x[b,i+di,j+dj,c] * flow[b,i,j,di*K+dj]
// B=8, H=W=256, C=64, K=5, Ho=Wo=252. All fp32.
//
// R9: single-shot LDS staging of the whole x tile.
// Session laws so far: (a) register prefetch rings are unschedulable on this
// compiler (R4/R7/R8: allocator sinks loads regardless of budget);
// (b) global_load_lds DMA explodes traffic on this stencil (R3);
// (c) plain reg->LDS staging is traffic-clean (R5 counters) but dies if it
//     needs double-buffer register convoys (VGPR 160, 5 barrier drains).
// R9 therefore: ONE burst of 17 independent coalesced loads/thread ->
// ds_write -> ONE barrier -> all-LDS compute. Latency hidden by 3 resident
// blocks/CU (R=4 -> 50 KB LDS), not by intra-wave scheduling.
//  - x LDS reads swizzled q' = (q+px)&15: kills 4-way jj-lane bank conflict
//    (px stride = 64 words); stage writes stay linear/conflict-free.
//  - flow LDS: FROW=8 pad, b128+b32 reads, jj lanes on banks {0,8,16,24}.
//  - NT output stores (out never re-read; preserve L3 for x).

constexpr int B  = 8;
constexpr int H  = 256;
constexpr int W  = 256;
constexpr int C  = 64;
constexpr int K  = 5;
constexpr int Ho = H - K + 1;            // 252
constexpr int Wo = W - K + 1;            // 252
constexpr int CQ = C / 4;                // 16 float4 quads per pixel
constexpr int R  = 4;                    // output rows per block (Ho % R == 0)
constexpr int SEG = Ho / R;              // 63 row segments
constexpr int JT  = 16;                  // j-pixels per block (16 j x 16 q)
constexpr int JB  = (Wo + JT - 1) / JT;  // 16 j blocks (last partial)
constexpr int NR  = R + K - 1;           // 8 x rows staged per block
constexpr int PX  = JT + K - 1;          // 20 x-pixels staged per row
constexpr int FROW = 8;                  // filter row padded 5 -> 8 floats
constexpr int XCHUNK = NR * PX * CQ;     // 2560 float4 = 40 KiB
constexpr int XSTEPS = XCHUNK / 256;     // 10 (exact)
constexpr int FELEMS = R * JT * K * K;   // 1600
constexpr int FSTEPS = (FELEMS + 255) / 256;  // 7

typedef float vf4 __attribute__((ext_vector_type(4)));

__global__ __launch_bounds__(256) void dfl_kernel(
    const float* __restrict__ x,
    const float* __restrict__ flow,
    float* __restrict__ out)
{
    __shared__ float4 sx[XCHUNK];            // 40 KiB x tile (q-swizzled)
    __shared__ float  sf[R * JT * K * FROW]; // 10 KiB padded flow

    const int t  = threadIdx.x;
    const int q  = t & (CQ - 1);          // channel quad 0..15
    const int jj = t >> 4;                // j within block 0..15

    int bid = blockIdx.x;
    const int jb  = bid % JB;  bid /= JB;
    const int seg = bid % SEG; bid /= SEG;
    const int b   = bid;

    const int j0 = jb * JT;
    const int j  = j0 + jj;
    const int i0 = seg * R;

    // ---- burst-issue ALL global loads (17/thread, independent) ----
    const float4* xg = (const float4*)x;
    float4 xs[XSTEPS];
    #pragma unroll
    for (int s = 0; s < XSTEPS; ++s) {
        const int c   = s * 256 + t;          // 0..2559, exact
        const int rr  = c / (PX * CQ);        // staged row 0..7
        const int rem = c - rr * (PX * CQ);
        const int px  = rem >> 4;             // pixel 0..19
        const int qd  = rem & 15;
        int gpx = j0 + px; if (gpx > W - 1) gpx = W - 1;  // edge clamp
        xs[s] = xg[((size_t)(b * H + i0 + rr) * W + gpx) * CQ + qd];
    }
    float fs[FSTEPS];
    {
        const float* fsrc = flow + ((size_t)(b * Ho + i0) * Wo + j0) * (K * K);
        #pragma unroll
        for (int s = 0; s < FSTEPS; ++s) {
            const int e = s * 256 + t;
            float v = 0.f;
            if (e < FELEMS) {
                const int ii  = e / (JT * K * K);
                const int rem = e - ii * (JT * K * K);
                const int pj  = rem / (K * K);
                const int tap = rem - pj * (K * K);
                if (j0 + pj < Wo)             // guard: last j-block OOB
                    v = fsrc[(size_t)ii * (Wo * K * K) + pj * (K * K) + tap];
            }
            fs[s] = v;
        }
    }

    // ---- commit to LDS (vmcnt waits pipelined by compiler) ----
    #pragma unroll
    for (int s = 0; s < XSTEPS; ++s) {
        const int c   = s * 256 + t;
        const int rr  = c / (PX * CQ);
        const int rem = c - rr * (PX * CQ);
        const int px  = rem >> 4;
        const int qd  = rem & 15;
        sx[(rr * PX + px) * CQ + ((qd + px) & 15)] = xs[s];  // q-rotate swizzle
    }
    #pragma unroll
    for (int s = 0; s < FSTEPS; ++s) {
        const int e = s * 256 + t;
        if (e < FELEMS) {
            const int ii  = e / (JT * K * K);
            const int rem = e - ii * (JT * K * K);
            const int pj  = rem / (K * K);
            const int tap = rem - pj * (K * K);
            const int di  = tap / K;
            const int dj  = tap - di * K;
            sf[((ii * JT + pj) * K + di) * FROW + dj] = fs[s];
        }
    }
    __syncthreads();                          // the ONLY barrier

    // ---- compute: everything from LDS ----
    float4 acc[R];
    #pragma unroll
    for (int ii = 0; ii < R; ++ii) acc[ii] = make_float4(0.f, 0.f, 0.f, 0.f);

    int qs[K];                                // swizzled q per dj (static idx)
    #pragma unroll
    for (int d = 0; d < K; ++d) qs[d] = (q + jj + d) & 15;

    #pragma unroll
    for (int r = 0; r < NR; ++r) {
        float4 xv[K];
        #pragma unroll
        for (int dj = 0; dj < K; ++dj)
            xv[dj] = sx[(r * PX + jj + dj) * CQ + qs[dj]];
        #pragma unroll
        for (int ii = 0; ii < R; ++ii) {
            const int di = r - ii;            // tap row for output ii
            if (di < 0 || di >= K) continue;  // compile-time resolved
            const float* fp = &sf[((ii * JT + jj) * K + di) * FROW];
            const vf4   w4 = *(const vf4*)fp; // ds_read_b128
            const float w5 = fp[4];           // ds_read_b32
            const float wt[K] = {w4.x, w4.y, w4.z, w4.w, w5};
            #pragma unroll
            for (int dj = 0; dj < K; ++dj) {
                acc[ii].x += xv[dj].x * wt[dj];
                acc[ii].y += xv[dj].y * wt[dj];
                acc[ii].z += xv[dj].z * wt[dj];
                acc[ii].w += xv[dj].w * wt[dj];
            }
        }
    }

    if (j < Wo) {
        float* ob = out + (((size_t)(b * Ho + i0) * Wo + j) * CQ + q) * 4;
        #pragma unroll
        for (int ii = 0; ii < R; ++ii) {
            vf4 v = {acc[ii].x, acc[ii].y, acc[ii].z, acc[ii].w};
            __builtin_nontemporal_store(v, (vf4*)(ob + (size_t)ii * (Wo * CQ) * 4));
        }
    }
}

extern "C" void kernel_launch(void* const* d_in, const int* in_sizes, int n_in,
                              void* d_out, int out_size, void* d_ws, size_t ws_size,
                              hipStream_t stream) {
    const float* x    = (const float*)d_in[0];
    const float* flow = (const float*)d_in[1];
    // d_in[2] is ksize (scalar), fixed at 5 — baked in as constexpr.
    float* out = (float*)d_out;

    const int grid = B * SEG * JB;        // 8 * 63 * 16 = 8064 blocks
    dfl_kernel<<<grid, 256, 0, stream>>>(x, flow, out);
}